// Round 2
// baseline (356.848 us; speedup 1.0000x reference)
//
#include <hip/hip_runtime.h>
#include <hip/hip_bf16.h>
#include <math.h>

// Problem constants
#define BQ 4
#define NQ 100
#define MQ 50
#define HWSZ 65536
#define NP 128   // padded N (2 z-blocks x 4 tiles x 16)
#define MP 64    // padded M (4 x 16)
#define BK 64    // K depth per LDS stage
#define LDA 72   // LDS row stride in bf16 elems (64 + 8 pad)
#define DCLAMP 13.8155106f   // logit(1-1e-6) = -logit(1e-6)

typedef __attribute__((ext_vector_type(8))) short short8;
typedef __attribute__((ext_vector_type(4))) float f32x4;

__device__ inline unsigned short f2bf(float f) {
    unsigned u = __float_as_uint(f);
    unsigned r = u + 0x7FFFu + ((u >> 16) & 1u);   // RTNE
    return (unsigned short)(r >> 16);
}

// d = log(pm)-log(1-pm) = clamp(x, +-13.8155) EXACTLY (logit o clip o sigmoid).
// pm = clip(sigmoid(x)) = sigmoid(clamp(x)); l1m = log(1-pm) = -log(1+e^xc).
__device__ inline void xform2(float x, float& d, float& pm, float& l1m) {
    float xc = fminf(fmaxf(x, -DCLAMP), DCLAMP);
    d = xc;
    float e = __expf(xc);                       // in [1e-6, 1e6], no overflow
    float r = __builtin_amdgcn_rcpf(1.0f + e);
    pm = e * r;
    l1m = -__logf(1.0f + e);
}

// grid (nch, 4, 2). Block (chunk, b, nz) handles K range [chunk*Kc, ...) and
// N rows [nz*64, nz*64+64). Produces partial S1 = sum d*tm, S2 = sum pm*tm,
// row sums (l1m, pm) per n, col sums (tm) per m (nz==0 only).
__global__ __launch_bounds__(256, 4)
void matcher_main(const float* __restrict__ pred_masks,  // [4][100][65536]
                  const float* __restrict__ tgt_masks,   // [4][50][65536]
                  float* __restrict__ part1,             // [4][nch][128][64]
                  float* __restrict__ part2,             // [4][nch][128][64]
                  float* __restrict__ rspart,            // [4][nch][128][2]
                  float* __restrict__ tspart,            // [4][nch][64]
                  int nch, int Kc)
{
    __shared__ __align__(16) unsigned short ldsAd[64 * LDA];
    __shared__ __align__(16) unsigned short ldsApm[64 * LDA];
    __shared__ __align__(16) unsigned short ldsB[64 * LDA];

    const int chunk = blockIdx.x;
    const int b     = blockIdx.y;
    const int nz    = blockIdx.z;
    const int ROW0  = nz * 64;
    const int t     = threadIdx.x;
    const int lane  = t & 63;
    const int wv    = t >> 6;    // wave id = m-tile
    const int kq    = t & 15;    // k-quad (4 floats) within BK
    const int rg    = t >> 4;    // row group 0..15

    const long kbase0 = (long)chunk * Kc;
    const int nsteps = Kc / BK;

    f32x4 acc1[4], acc2[4];
    #pragma unroll
    for (int i = 0; i < 4; i++) { acc1[i] = (f32x4){0.f,0.f,0.f,0.f}; acc2[i] = (f32x4){0.f,0.f,0.f,0.f}; }
    float rsl[4] = {0.f,0.f,0.f,0.f}, rsp[4] = {0.f,0.f,0.f,0.f}, ts4[4] = {0.f,0.f,0.f,0.f};

    float4 apf[4], bpf[4];

    // prologue: prefetch step 0
    {
        const long kb = kbase0;
        #pragma unroll
        for (int i = 0; i < 4; i++) {
            const int rglob = ROW0 + i * 16 + rg;
            apf[i] = make_float4(0.f, 0.f, 0.f, 0.f);
            if (rglob < NQ)
                apf[i] = *(const float4*)&pred_masks[(((long)(b * NQ + rglob)) << 16) + kb + kq * 4];
            const int brow = i * 16 + rg;
            bpf[i] = make_float4(0.f, 0.f, 0.f, 0.f);
            if (brow < MQ)
                bpf[i] = *(const float4*)&tgt_masks[(((long)(b * MQ + brow)) << 16) + kb + kq * 4];
        }
    }

    const int aoff = (lane & 15) * LDA;
    const int koff = (lane >> 4) * 8;

    for (int s = 0; s < nsteps; ++s) {
        // ---- transform prefetched regs -> LDS ----
        #pragma unroll
        for (int i = 0; i < 4; i++) {
            const float4 v = apf[i];
            float d0,d1,d2,d3, p0,p1,p2,p3, l;
            xform2(v.x, d0, p0, l); rsl[i] += l; rsp[i] += p0;
            xform2(v.y, d1, p1, l); rsl[i] += l; rsp[i] += p1;
            xform2(v.z, d2, p2, l); rsl[i] += l; rsp[i] += p2;
            xform2(v.w, d3, p3, l); rsl[i] += l; rsp[i] += p3;
            const int row = i * 16 + rg;
            *(uint2*)&ldsAd[row * LDA + kq * 4] = make_uint2(
                (unsigned)f2bf(d0) | ((unsigned)f2bf(d1) << 16),
                (unsigned)f2bf(d2) | ((unsigned)f2bf(d3) << 16));
            *(uint2*)&ldsApm[row * LDA + kq * 4] = make_uint2(
                (unsigned)f2bf(p0) | ((unsigned)f2bf(p1) << 16),
                (unsigned)f2bf(p2) | ((unsigned)f2bf(p3) << 16));
        }
        #pragma unroll
        for (int i = 0; i < 4; i++) {
            const float4 v = bpf[i];
            if (nz == 0) ts4[i] += v.x + v.y + v.z + v.w;
            const int row = i * 16 + rg;
            *(uint2*)&ldsB[row * LDA + kq * 4] = make_uint2(
                (unsigned)f2bf(v.x) | ((unsigned)f2bf(v.y) << 16),
                (unsigned)f2bf(v.z) | ((unsigned)f2bf(v.w) << 16));
        }

        __syncthreads();

        // ---- prefetch next step (latency hidden behind MFMA + other waves) ----
        if (s + 1 < nsteps) {
            const long kb = kbase0 + (long)(s + 1) * BK;
            #pragma unroll
            for (int i = 0; i < 4; i++) {
                const int rglob = ROW0 + i * 16 + rg;
                apf[i] = make_float4(0.f, 0.f, 0.f, 0.f);
                if (rglob < NQ)
                    apf[i] = *(const float4*)&pred_masks[(((long)(b * NQ + rglob)) << 16) + kb + kq * 4];
                const int brow = i * 16 + rg;
                bpf[i] = make_float4(0.f, 0.f, 0.f, 0.f);
                if (brow < MQ)
                    bpf[i] = *(const float4*)&tgt_masks[(((long)(b * MQ + brow)) << 16) + kb + kq * 4];
            }
        }

        // ---- MFMA: wave wv = m-tile, 4 n-tiles, both matrices ----
        #pragma unroll
        for (int ks = 0; ks < 2; ++ks) {
            const int kk = ks * 32 + koff;
            const short8 bf = *(const short8*)&ldsB[(wv * 16) * LDA + aoff + kk];
            #pragma unroll
            for (int nt = 0; nt < 4; ++nt) {
                const short8 a1 = *(const short8*)&ldsAd[(nt * 16) * LDA + aoff + kk];
                acc1[nt] = __builtin_amdgcn_mfma_f32_16x16x32_bf16(a1, bf, acc1[nt], 0, 0, 0);
                const short8 a2 = *(const short8*)&ldsApm[(nt * 16) * LDA + aoff + kk];
                acc2[nt] = __builtin_amdgcn_mfma_f32_16x16x32_bf16(a2, bf, acc2[nt], 0, 0, 0);
            }
        }

        __syncthreads();
    }

    // ---- store C partials: C/D layout col=lane&15, row=(lane>>4)*4+reg ----
    const long pbase = ((long)(b * nch + chunk)) * NP * MP;
    const int mloc = wv * 16 + (lane & 15);
    const int nr0 = (lane >> 4) * 4;
    #pragma unroll
    for (int nt = 0; nt < 4; ++nt) {
        #pragma unroll
        for (int r = 0; r < 4; ++r) {
            const int ng = ROW0 + nt * 16 + nr0 + r;
            if (ng < NQ) {
                part1[pbase + ng * MP + mloc] = acc1[nt][r];
                part2[pbase + ng * MP + mloc] = acc2[nt][r];
            }
        }
    }

    // ---- row/col sum reductions via LDS (safe: loop ended with syncthreads) ----
    float2* red = (float2*)ldsAd;   // [64][16]
    #pragma unroll
    for (int i = 0; i < 4; i++) red[(i * 16 + rg) * 16 + kq] = make_float2(rsl[i], rsp[i]);
    float* redt = (float*)ldsApm;   // [64][16]
    #pragma unroll
    for (int i = 0; i < 4; i++) redt[(i * 16 + rg) * 16 + kq] = ts4[i];
    __syncthreads();

    if (t < 64) {
        float a = 0.f, c = 0.f;
        #pragma unroll
        for (int j = 0; j < 16; j++) { float2 v = red[t * 16 + j]; a += v.x; c += v.y; }
        const long rb = ((long)(b * nch + chunk) * NP + ROW0 + t) * 2;
        rspart[rb + 0] = a;
        rspart[rb + 1] = c;
    }
    if (nz == 0 && t >= 64 && t < 128) {
        const int m = t - 64;
        float a = 0.f;
        #pragma unroll
        for (int j = 0; j < 16; j++) a += redt[m * 16 + j];
        tspart[(long)(b * nch + chunk) * MP + m] = a;
    }
}

// Epilogue: one block per (b,n); parallel chunk reduction + cost combine.
__global__ __launch_bounds__(256)
void matcher_epilogue(const float* __restrict__ pred_logits, // [4][100][2]
                      const float* __restrict__ pred_style,  // [4][100][4]
                      const int*   __restrict__ styles,      // [4][50]
                      const float* __restrict__ part1,
                      const float* __restrict__ part2,
                      const float* __restrict__ rspart,
                      const float* __restrict__ tspart,
                      float* __restrict__ out, int nch)
{
    __shared__ float red1[4][64], red2[4][64], redt[4][64];
    __shared__ float slw[4], spw[4];

    const int blk = blockIdx.x;          // 0..399
    const int b = blk / NQ, n = blk % NQ;
    const int t = threadIdx.x;
    const int m = t & 63, cg = t >> 6;   // cg in 0..3

    float S1 = 0.f, S2 = 0.f, St = 0.f;
    for (int c = cg; c < nch; c += 4) {
        const long base = ((long)(b * nch + c) * NP + n) * MP + m;
        S1 += part1[base];
        S2 += part2[base];
        St += tspart[(long)(b * nch + c) * MP + m];
    }
    red1[cg][m] = S1; red2[cg][m] = S2; redt[cg][m] = St;

    // Sl/Sp across chunks (nch <= 128): threads 0..nch-1 load, shuffle-reduce
    float sl = 0.f, sp = 0.f;
    if (t < nch) {
        const float2 v = *(const float2*)&rspart[((long)(b * nch + t) * NP + n) * 2];
        sl = v.x; sp = v.y;
    }
    #pragma unroll
    for (int off = 32; off; off >>= 1) { sl += __shfl_down(sl, off); sp += __shfl_down(sp, off); }
    if ((t & 63) == 0) { slw[t >> 6] = sl; spw[t >> 6] = sp; }
    __syncthreads();

    if (t < MQ) {
        const float Sl = slw[0] + slw[1] + slw[2] + slw[3];
        const float Sp = spw[0] + spw[1] + spw[2] + spw[3];
        const float s1 = red1[0][t] + red1[1][t] + red1[2][t] + red1[3][t];
        const float s2 = red2[0][t] + red2[1][t] + red2[2][t] + red2[3][t];
        const float st = redt[0][t] + redt[1][t] + redt[2][t] + redt[3][t];

        // classification: -softmax(logits)[1]
        const float l0 = pred_logits[(b * NQ + n) * 2 + 0];
        const float l1 = pred_logits[(b * NQ + n) * 2 + 1];
        const float p1 = 1.0f / (1.0f + __expf(l0 - l1));

        // style: -softmax(style)[sid]
        const float* stp = &pred_style[(b * NQ + n) * 4];
        const float v0 = stp[0], v1 = stp[1], v2 = stp[2], v3 = stp[3];
        const float mx = fmaxf(fmaxf(v0, v1), fmaxf(v2, v3));
        const float e0 = __expf(v0 - mx), e1 = __expf(v1 - mx),
                    e2 = __expf(v2 - mx), e3 = __expf(v3 - mx);
        const float esum = e0 + e1 + e2 + e3;
        int sid = styles[b * MQ + t];
        sid = min(max(sid, 0), 3);
        const float ps = (sid == 0 ? e0 : sid == 1 ? e1 : sid == 2 ? e2 : e3) / esum;

        const float cost_mask = -(s1 + Sl) * (1.0f / (float)HWSZ);
        const float dice = 1.0f - (2.0f * s2 + 1.0f) / (Sp + st + 1.0f);

        float c = 2.0f * (-p1) + 5.0f * cost_mask + 5.0f * dice + 1.0f * (-ps);
        if (isnan(c)) c = 10000.0f;
        else if (isinf(c)) c = (c > 0.f) ? 10000.0f : -10000.0f;
        out[(b * NQ + n) * MQ + t] = c;
    }
}

extern "C" void kernel_launch(void* const* d_in, const int* in_sizes, int n_in,
                              void* d_out, int out_size, void* d_ws, size_t ws_size,
                              hipStream_t stream) {
    const float* pred_logits = (const float*)d_in[0];
    const float* pred_masks  = (const float*)d_in[1];
    const float* pred_style  = (const float*)d_in[2];
    const float* tgt_masks   = (const float*)d_in[3];
    const int*   styles      = (const int*)d_in[4];
    float* out = (float*)d_out;

    // ws layout: part1/part2 [4][nch][128][64], rspart [4][nch][128][2], tspart [4][nch][64]
    int nch = 8;
    for (int cand = 128; cand >= 8; cand >>= 1) {
        size_t need = (size_t)cand * (2ull * BQ * NP * MP * 4ull
                                      + (size_t)BQ * NP * 2 * 4ull
                                      + (size_t)BQ * MP * 4ull);
        if (need <= ws_size) { nch = cand; break; }
    }
    const int Kc = HWSZ / nch;

    float* part1  = (float*)d_ws;
    float* part2  = part1 + (size_t)BQ * nch * NP * MP;
    float* rspart = part2 + (size_t)BQ * nch * NP * MP;
    float* tspart = rspart + (size_t)BQ * nch * NP * 2;

    dim3 grid(nch, BQ, 2);
    matcher_main<<<grid, 256, 0, stream>>>(pred_masks, tgt_masks, part1, part2, rspart, tspart, nch, Kc);

    matcher_epilogue<<<BQ * NQ, 256, 0, stream>>>(
        pred_logits, pred_style, styles, part1, part2, rspart, tspart, out, nch);
}

// Round 3
// 227.632 us; speedup vs baseline: 1.5677x; 1.5677x over previous
//
#include <hip/hip_runtime.h>
#include <hip/hip_bf16.h>
#include <math.h>

// Problem constants
#define BQ 4
#define NQ 100
#define MQ 50
#define HWSZ 65536
#define NP 112   // padded N rows in partials (7 x 16)
#define MP 64    // padded M (4 x 16)
#define BK 64    // K depth (f32 elems) per LDS stage
#define LDA 72   // LDS row stride in bf16 elems (64 + 8 pad; 144B stride -> 2-way banks, free)
#define DCLAMP 13.8155106f   // logit(1-1e-6) = -logit(1e-6)

typedef __attribute__((ext_vector_type(8))) short short8;
typedef __attribute__((ext_vector_type(4))) float f32x4;

// d = log(pm)-log(1-pm) = clamp(x, +-13.8155) EXACTLY (logit o clip o sigmoid).
// pm = sigmoid(clamp(x)); l1m = log(1-pm) = -log(1+e^xc).
__device__ __forceinline__ void xform2(float x, float& d, float& pm, float& l1m) {
    float xc = fminf(fmaxf(x, -DCLAMP), DCLAMP);
    d = xc;
    float e = __expf(xc);                       // in [1e-6, 1e6], no overflow
    float r = __builtin_amdgcn_rcpf(1.0f + e);
    pm = e * r;
    l1m = -__logf(1.0f + e);
}

// pack two floats -> two bf16 (RTNE) in one u32 (v_cvt_pk_bf16_f32 on gfx950)
__device__ __forceinline__ unsigned pk2(float a, float b) {
    __hip_bfloat162 h = __float22bfloat162_rn(float2{a, b});
    unsigned u;
    __builtin_memcpy(&u, &h, 4);
    return u;
}

// One block: K range [chunk*Kc, ...), N rows [ROW0, ROW0+16*NT).
// Produces partial S1 = sum d*tm, S2 = sum pm*tm over its K range,
// row-sum partials (l1m, pm) per n, and (DO_TS only) tm col sums per m.
template <int NT, int ROW0, bool DO_TS>
__device__ __forceinline__ void run_block(
    const float* __restrict__ pred_masks, const float* __restrict__ tgt_masks,
    float* __restrict__ part1, float* __restrict__ part2,
    float* __restrict__ rspart, float* __restrict__ tspart,
    int nch, int Kc, int chunk, int b,
    unsigned short* ldsAd, unsigned short* ldsApm, unsigned short* ldsB)
{
    const int t    = threadIdx.x;
    const int lane = t & 63;
    const int wv   = t >> 6;    // wave id = m-tile
    const int kq   = t & 15;    // 16B (4-float) chunk within BK
    const int rg   = t >> 4;    // row group 0..15

    const long kbase0 = (long)chunk * Kc;
    const int nsteps = Kc / BK;

    f32x4 acc1[NT], acc2[NT];
    #pragma unroll
    for (int i = 0; i < NT; i++) { acc1[i] = (f32x4){0.f,0.f,0.f,0.f}; acc2[i] = (f32x4){0.f,0.f,0.f,0.f}; }
    float rsl[NT], rsp[NT];
    #pragma unroll
    for (int i = 0; i < NT; i++) { rsl[i] = 0.f; rsp[i] = 0.f; }
    float ts4[4] = {0.f, 0.f, 0.f, 0.f};

    float4 apf[NT], bpf[4];

    // prologue: prefetch step 0
    {
        #pragma unroll
        for (int i = 0; i < NT; i++) {
            const int rglob = ROW0 + i * 16 + rg;
            apf[i] = (NT == 4 || rglob < NQ)
                ? *(const float4*)&pred_masks[(((long)(b * NQ + rglob)) << 16) + kbase0 + kq * 4]
                : make_float4(0.f, 0.f, 0.f, 0.f);
        }
        #pragma unroll
        for (int i = 0; i < 4; i++) {
            const int brow = i * 16 + rg;
            bpf[i] = (brow < MQ)
                ? *(const float4*)&tgt_masks[(((long)(b * MQ + brow)) << 16) + kbase0 + kq * 4]
                : make_float4(0.f, 0.f, 0.f, 0.f);
        }
    }

    const int aoff = (lane & 15) * LDA;
    const int koff = (lane >> 4) * 8;

    for (int s = 0; s < nsteps; ++s) {
        // ---- transform prefetched regs -> LDS ----
        #pragma unroll
        for (int i = 0; i < NT; i++) {
            const float4 v = apf[i];
            float d0,d1,d2,d3, p0,p1,p2,p3, l;
            xform2(v.x, d0, p0, l); rsl[i] += l; rsp[i] += p0;
            xform2(v.y, d1, p1, l); rsl[i] += l; rsp[i] += p1;
            xform2(v.z, d2, p2, l); rsl[i] += l; rsp[i] += p2;
            xform2(v.w, d3, p3, l); rsl[i] += l; rsp[i] += p3;
            const int row = i * 16 + rg;
            *(uint2*)&ldsAd[row * LDA + kq * 4]  = make_uint2(pk2(d0, d1), pk2(d2, d3));
            *(uint2*)&ldsApm[row * LDA + kq * 4] = make_uint2(pk2(p0, p1), pk2(p2, p3));
        }
        #pragma unroll
        for (int i = 0; i < 4; i++) {
            const float4 v = bpf[i];
            if (DO_TS) ts4[i] += v.x + v.y + v.z + v.w;
            const int row = i * 16 + rg;
            *(uint2*)&ldsB[row * LDA + kq * 4] = make_uint2(pk2(v.x, v.y), pk2(v.z, v.w));
        }

        __syncthreads();

        // ---- prefetch next step (in flight across the MFMA section) ----
        if (s + 1 < nsteps) {
            const long kb = kbase0 + (long)(s + 1) * BK;
            #pragma unroll
            for (int i = 0; i < NT; i++) {
                const int rglob = ROW0 + i * 16 + rg;
                apf[i] = (NT == 4 || rglob < NQ)
                    ? *(const float4*)&pred_masks[(((long)(b * NQ + rglob)) << 16) + kb + kq * 4]
                    : make_float4(0.f, 0.f, 0.f, 0.f);
            }
            #pragma unroll
            for (int i = 0; i < 4; i++) {
                const int brow = i * 16 + rg;
                bpf[i] = (brow < MQ)
                    ? *(const float4*)&tgt_masks[(((long)(b * MQ + brow)) << 16) + kb + kq * 4]
                    : make_float4(0.f, 0.f, 0.f, 0.f);
            }
        }

        // ---- MFMA: wave wv = m-tile, NT n-tiles, both matrices ----
        #pragma unroll
        for (int ks = 0; ks < 2; ++ks) {
            const int kk = ks * 32 + koff;
            const short8 bf = *(const short8*)&ldsB[(wv * 16) * LDA + aoff + kk];
            #pragma unroll
            for (int nt = 0; nt < NT; ++nt) {
                const short8 a1 = *(const short8*)&ldsAd[(nt * 16) * LDA + aoff + kk];
                acc1[nt] = __builtin_amdgcn_mfma_f32_16x16x32_bf16(a1, bf, acc1[nt], 0, 0, 0);
                const short8 a2 = *(const short8*)&ldsApm[(nt * 16) * LDA + aoff + kk];
                acc2[nt] = __builtin_amdgcn_mfma_f32_16x16x32_bf16(a2, bf, acc2[nt], 0, 0, 0);
            }
        }

        __syncthreads();
    }

    // ---- store C partials: C/D layout col=lane&15, row=(lane>>4)*4+reg ----
    // (pad rows >= NQ land in rows < NP of the partial buffer; never read)
    const long pbase = ((long)(b * nch + chunk)) * NP * MP;
    const int mloc = wv * 16 + (lane & 15);
    const int nr0 = (lane >> 4) * 4;
    #pragma unroll
    for (int nt = 0; nt < NT; ++nt) {
        #pragma unroll
        for (int r = 0; r < 4; ++r) {
            const int ng = ROW0 + nt * 16 + nr0 + r;
            part1[pbase + ng * MP + mloc] = acc1[nt][r];
            part2[pbase + ng * MP + mloc] = acc2[nt][r];
        }
    }

    // ---- row/col sum reductions via LDS (loop ended with syncthreads) ----
    float2* red = (float2*)ldsAd;   // [16*NT][16]
    #pragma unroll
    for (int i = 0; i < NT; i++) red[(i * 16 + rg) * 16 + kq] = make_float2(rsl[i], rsp[i]);
    float* redt = (float*)ldsApm;   // [64][16]
    if (DO_TS) {
        #pragma unroll
        for (int i = 0; i < 4; i++) redt[(i * 16 + rg) * 16 + kq] = ts4[i];
    }
    __syncthreads();

    if (t < 16 * NT) {
        float a = 0.f, c = 0.f;
        #pragma unroll
        for (int j = 0; j < 16; j++) { float2 v = red[t * 16 + j]; a += v.x; c += v.y; }
        const long rb = ((long)(b * nch + chunk) * NP + ROW0 + t) * 2;
        rspart[rb + 0] = a;
        rspart[rb + 1] = c;
    }
    if (DO_TS && t >= 64 && t < 128) {
        const int m = t - 64;
        float a = 0.f;
        #pragma unroll
        for (int j = 0; j < 16; j++) a += redt[m * 16 + j];
        tspart[(long)(b * nch + chunk) * MP + m] = a;
    }
}

__global__ __launch_bounds__(256, 2)
void matcher_main(const float* __restrict__ pred_masks,  // [4][100][65536]
                  const float* __restrict__ tgt_masks,   // [4][50][65536]
                  float* __restrict__ part1,             // [4][nch][112][64]
                  float* __restrict__ part2,             // [4][nch][112][64]
                  float* __restrict__ rspart,            // [4][nch][112][2]
                  float* __restrict__ tspart,            // [4][nch][64]
                  int nch, int Kc)
{
    __shared__ __align__(16) unsigned short ldsAd[64 * LDA];
    __shared__ __align__(16) unsigned short ldsApm[64 * LDA];
    __shared__ __align__(16) unsigned short ldsB[64 * LDA];

    const int chunk = blockIdx.x;
    const int b     = blockIdx.y;
    if (blockIdx.z == 0)
        run_block<4, 0, true>(pred_masks, tgt_masks, part1, part2, rspart, tspart,
                              nch, Kc, chunk, b, ldsAd, ldsApm, ldsB);
    else
        run_block<3, 64, false>(pred_masks, tgt_masks, part1, part2, rspart, tspart,
                                nch, Kc, chunk, b, ldsAd, ldsApm, ldsB);
}

// Epilogue: one block per (b,n); parallel chunk reduction + cost combine.
__global__ __launch_bounds__(256)
void matcher_epilogue(const float* __restrict__ pred_logits, // [4][100][2]
                      const float* __restrict__ pred_style,  // [4][100][4]
                      const int*   __restrict__ styles,      // [4][50]
                      const float* __restrict__ part1,
                      const float* __restrict__ part2,
                      const float* __restrict__ rspart,
                      const float* __restrict__ tspart,
                      float* __restrict__ out, int nch)
{
    __shared__ float red1[4][64], red2[4][64], redt[4][64];
    __shared__ float slw[4], spw[4];

    const int blk = blockIdx.x;          // 0..399
    const int b = blk / NQ, n = blk % NQ;
    const int t = threadIdx.x;
    const int m = t & 63, cg = t >> 6;   // cg in 0..3

    float S1 = 0.f, S2 = 0.f, St = 0.f;
    for (int c = cg; c < nch; c += 4) {
        const long base = ((long)(b * nch + c) * NP + n) * MP + m;
        S1 += part1[base];
        S2 += part2[base];
        St += tspart[(long)(b * nch + c) * MP + m];
    }
    red1[cg][m] = S1; red2[cg][m] = S2; redt[cg][m] = St;

    // Sl/Sp across chunks (nch <= 128): threads 0..nch-1 load, shuffle-reduce
    float sl = 0.f, sp = 0.f;
    if (t < nch) {
        const float2 v = *(const float2*)&rspart[((long)(b * nch + t) * NP + n) * 2];
        sl = v.x; sp = v.y;
    }
    #pragma unroll
    for (int off = 32; off; off >>= 1) { sl += __shfl_down(sl, off); sp += __shfl_down(sp, off); }
    if ((t & 63) == 0) { slw[t >> 6] = sl; spw[t >> 6] = sp; }
    __syncthreads();

    if (t < MQ) {
        const float Sl = slw[0] + slw[1] + slw[2] + slw[3];
        const float Sp = spw[0] + spw[1] + spw[2] + spw[3];
        const float s1 = red1[0][t] + red1[1][t] + red1[2][t] + red1[3][t];
        const float s2 = red2[0][t] + red2[1][t] + red2[2][t] + red2[3][t];
        const float st = redt[0][t] + redt[1][t] + redt[2][t] + redt[3][t];

        // classification: -softmax(logits)[1]
        const float l0 = pred_logits[(b * NQ + n) * 2 + 0];
        const float l1 = pred_logits[(b * NQ + n) * 2 + 1];
        const float p1 = 1.0f / (1.0f + __expf(l0 - l1));

        // style: -softmax(style)[sid]
        const float* stp = &pred_style[(b * NQ + n) * 4];
        const float v0 = stp[0], v1 = stp[1], v2 = stp[2], v3 = stp[3];
        const float mx = fmaxf(fmaxf(v0, v1), fmaxf(v2, v3));
        const float e0 = __expf(v0 - mx), e1 = __expf(v1 - mx),
                    e2 = __expf(v2 - mx), e3 = __expf(v3 - mx);
        const float esum = e0 + e1 + e2 + e3;
        int sid = styles[b * MQ + t];
        sid = min(max(sid, 0), 3);
        const float ps = (sid == 0 ? e0 : sid == 1 ? e1 : sid == 2 ? e2 : e3) / esum;

        const float cost_mask = -(s1 + Sl) * (1.0f / (float)HWSZ);
        const float dice = 1.0f - (2.0f * s2 + 1.0f) / (Sp + st + 1.0f);

        float c = 2.0f * (-p1) + 5.0f * cost_mask + 5.0f * dice + 1.0f * (-ps);
        if (isnan(c)) c = 10000.0f;
        else if (isinf(c)) c = (c > 0.f) ? 10000.0f : -10000.0f;
        out[(b * NQ + n) * MQ + t] = c;
    }
}

extern "C" void kernel_launch(void* const* d_in, const int* in_sizes, int n_in,
                              void* d_out, int out_size, void* d_ws, size_t ws_size,
                              hipStream_t stream) {
    const float* pred_logits = (const float*)d_in[0];
    const float* pred_masks  = (const float*)d_in[1];
    const float* pred_style  = (const float*)d_in[2];
    const float* tgt_masks   = (const float*)d_in[3];
    const int*   styles      = (const int*)d_in[4];
    float* out = (float*)d_out;

    // ws layout: part1/part2 [4][nch][112][64], rspart [4][nch][112][2], tspart [4][nch][64]
    int nch = 8;
    for (int cand = 128; cand >= 8; cand >>= 1) {
        size_t need = (size_t)cand * (2ull * BQ * NP * MP * 4ull
                                      + (size_t)BQ * NP * 2 * 4ull
                                      + (size_t)BQ * MP * 4ull);
        if (need <= ws_size) { nch = cand; break; }
    }
    const int Kc = HWSZ / nch;

    float* part1  = (float*)d_ws;
    float* part2  = part1 + (size_t)BQ * nch * NP * MP;
    float* rspart = part2 + (size_t)BQ * nch * NP * MP;
    float* tspart = rspart + (size_t)BQ * nch * NP * 2;

    dim3 grid(nch, BQ, 2);
    matcher_main<<<grid, 256, 0, stream>>>(pred_masks, tgt_masks, part1, part2, rspart, tspart, nch, Kc);

    matcher_epilogue<<<BQ * NQ, 256, 0, stream>>>(
        pred_logits, pred_style, styles, part1, part2, rspart, tspart, out, nch);
}